// Round 1
// baseline (2161.909 us; speedup 1.0000x reference)
//
#include <hip/hip_runtime.h>
#include <math.h>

#define NB 256
#define NS 64
#define NH 128
#define NZ 128
#define NSTEPS 63
#define PITCH 132  // preA/preP row pitch

// +4 floats of pad per 32-float chunk: chunk q starts at 36q -> distinct banks per q
__device__ __forceinline__ int padh(int i) { return i + ((i >> 5) << 2); }

// fast tanh for the non-recurrent score paths (C/G): v_exp + v_rcp, ~1e-7 abs err
__device__ __forceinline__ float ftanh(float x) {
  float e = __expf(2.0f * x);
  return 1.0f - 2.0f * __builtin_amdgcn_rcpf(e + 1.0f);
}

struct SM {
  float preA[NS * PITCH];  // IH @ W_a[:H]   (per-b)
  float preP[NS * PITCH];  // IH @ Wp[:H]    (per-b)
  float hbuf[2][144];      // ping-pong h, padded layout
  float atth[144];         // padded
  float ptrh[144];         // padded
  float va[144];           // padded
  float vpv[144];          // padded
  float fcop[144];         // padded
  float ctx[NH];
  float fc1[2 * NH];
  float zw1[2 * NH];       // Z @ W1[H:H+ZD] (per-b)
  float Gpre[3 * 384];     // [W_emb;b_emb] @ W_ih^T (+b_ih)
  float E1ref[3 * 256];    // [W_emb;b_emb] @ W1[2H:3H] (+b1)
  float bhh[384];
  float b2s[NH];
  float attn[NS];
  float maskv[NS];
  float inst[2 * NS];      // instance[b] cached (refin updates)
  int   sol[NS];           // solution[b] cached
  float red[2048];         // partial-reduction scratch (E1/E2) + scores
  float refin[4];
};

__global__ __launch_bounds__(512, 2) void decoder_kernel(
    const float* __restrict__ instance, const int* __restrict__ solution,
    const float* __restrict__ Z, const float* __restrict__ IH,
    const float* __restrict__ last_hh, const float* __restrict__ W_emb,
    const float* __restrict__ b_emb, const float* __restrict__ W_ih,
    const float* __restrict__ W_hh, const float* __restrict__ b_ih,
    const float* __restrict__ b_hh, const float* __restrict__ W_a,
    const float* __restrict__ v_a, const float* __restrict__ W1,
    const float* __restrict__ b1, const float* __restrict__ W2,
    const float* __restrict__ b2, const float* __restrict__ Wp,
    const float* __restrict__ vp, float* __restrict__ out) {
  extern __shared__ float smraw[];
  SM& sm = *reinterpret_cast<SM*>(smraw);
  const int b = blockIdx.x;
  const int t = threadIdx.x;
  const float* ihb = IH + b * NS * NH;

  // ---------- thread-role constants ----------
  const int o4 = t >> 2, q4 = t & 3;          // quad layout: 128 outs x 4 k-chunks (intra-wave)
  const int s8 = t >> 3, q8 = t & 7;          // octet layout: 64 rows x 8 k-chunks (C,G)
  const int po8 = 16 * q8 + ((q8 >> 1) << 2); // padded base of 16-float chunk q8
  const int ob = (t & 31) * 4, qB = t >> 5;   // E2 partials (streamed)
  const int oE1 = (t & 63) * 4, qE1 = t >> 6; // E1 partials (streamed)

  // ---------- persistent register-cached weights ----------
  float4 whr[8], whz[8], whn[8];  // W_hh rows o4 (r,z,n), cols [32q4,32q4+32)
  {
    const float* br = W_hh + (0 * NH + o4) * NH + 32 * q4;
    const float* bz = W_hh + (1 * NH + o4) * NH + 32 * q4;
    const float* bn = W_hh + (2 * NH + o4) * NH + 32 * q4;
#pragma unroll
    for (int j = 0; j < 8; ++j) {
      whr[j] = *(const float4*)(br + 4 * j);
      whz[j] = *(const float4*)(bz + 4 * j);
      whn[j] = *(const float4*)(bn + 4 * j);
    }
  }
  float wa2r[32], wpr[32];  // W_a[H+k][o4], Wp[H+k][o4] for k in [32q4,32q4+32)
#pragma unroll
  for (int k = 0; k < 32; ++k) wa2r[k] = W_a[(NH + 32 * q4 + k) * NH + o4];
#pragma unroll
  for (int k = 0; k < 32; ++k) wpr[k] = Wp[(NH + 32 * q4 + k) * NH + o4];
  float ihr[16];  // IH[s][o4] for s in [16q4,16q4+16)
#pragma unroll
  for (int s = 0; s < 16; ++s) ihr[s] = ihb[(16 * q4 + s) * NH + o4];

  // ---------- startup: fill LDS ----------
  if (t < NS) {
    sm.maskv[t] = 1.0f;
    sm.sol[t] = solution[b * NS + t];
  }
  if (t < 2 * NS) sm.inst[t] = instance[b * 2 * NS + t];
  if (t < NH) {
    sm.hbuf[0][padh(t)] = last_hh[b * NH + t];
    sm.b2s[t] = b2[t];
    sm.va[padh(t)] = v_a[t];
    sm.vpv[padh(t)] = vp[t];
  }
  if (t < 384) sm.bhh[t] = b_hh[t];
  // zw1[o] = Z[b] . W1[H:H+ZD, o]
  if (t < 256) {
    const float* zb = Z + b * NZ;
    float a0 = 0.f, a1 = 0.f;
#pragma unroll 4
    for (int k = 0; k < NZ; k += 2) {
      a0 += zb[k] * W1[(NH + k) * 256 + t];
      a1 += zb[k + 1] * W1[(NH + k + 1) * 256 + t];
    }
    sm.zw1[t] = a0 + a1;
  }
  // Gpre[c][o3] = [W_emb;b_emb][c] . W_ih[o3,:]  (+ b_ih for c=2)
  if (t < 384) {
    const float* wi = W_ih + t * NH;
    float g0 = 0.f, g1 = 0.f, g2 = 0.f;
#pragma unroll 4
    for (int k4 = 0; k4 < 32; ++k4) {
      float4 w = *(const float4*)(wi + 4 * k4);
      float4 e0 = *(const float4*)(W_emb + 4 * k4);
      float4 e1 = *(const float4*)(W_emb + NH + 4 * k4);
      float4 eb = *(const float4*)(b_emb + 4 * k4);
      g0 += w.x * e0.x + w.y * e0.y + w.z * e0.z + w.w * e0.w;
      g1 += w.x * e1.x + w.y * e1.y + w.z * e1.z + w.w * e1.w;
      g2 += w.x * eb.x + w.y * eb.y + w.z * eb.z + w.w * eb.w;
    }
    sm.Gpre[t] = g0;
    sm.Gpre[384 + t] = g1;
    sm.Gpre[768 + t] = g2 + b_ih[t];
  }
  // E1ref[c][o] = [W_emb;b_emb][c] . W1[2H+k, o]  (+ b1 for c=2)
  if (t < 256) {
    float e0 = 0.f, e1 = 0.f, e2 = 0.f;
#pragma unroll 4
    for (int k = 0; k < NH; ++k) {
      float w = W1[(256 + k) * 256 + t];
      e0 += W_emb[k] * w;
      e1 += W_emb[NH + k] * w;
      e2 += b_emb[k] * w;
    }
    sm.E1ref[t] = e0;
    sm.E1ref[256 + t] = e1;
    sm.E1ref[512 + t] = e2 + b1[t];
  }
  // preA / preP
  for (int o = t; o < NS * NH; o += 512) {
    int s = o >> 7, j = o & 127;
    const float* row = ihb + s * NH;
    float a0 = 0.f, a1 = 0.f, p0 = 0.f, p1 = 0.f;
#pragma unroll 4
    for (int k = 0; k < NH; k += 2) {
      float r0 = row[k], r1 = row[k + 1];
      a0 += r0 * W_a[k * NH + j];
      a1 += r1 * W_a[(k + 1) * NH + j];
      p0 += r0 * Wp[k * NH + j];
      p1 += r1 * Wp[(k + 1) * NH + j];
    }
    sm.preA[s * PITCH + j] = a0 + a1;
    sm.preP[s * PITCH + j] = p0 + p1;
  }
  __syncthreads();
  if (t == 0) {
    int s0 = sm.sol[0];
    sm.maskv[s0] = 0.0f;
    sm.refin[0] = sm.inst[2 * s0];
    sm.refin[1] = sm.inst[2 * s0 + 1];
    out[b * NS] = (float)s0;
  }

  // ---------- 63 sequential decode steps ----------
  int cur = 0;
  for (int step = 1; step <= NSTEPS; ++step) {
    __syncthreads();
    // A: gh = W_hh @ h (reg weights), quad-shfl reduce, gates fused -> hbuf[cur^1]
    {
      float ar = 0.f, az = 0.f, an = 0.f;
      const float* hp = sm.hbuf[cur] + 36 * q4;
#pragma unroll
      for (int j = 0; j < 8; ++j) {
        float4 hv = *(const float4*)(hp + 4 * j);
        ar += hv.x * whr[j].x + hv.y * whr[j].y + hv.z * whr[j].z + hv.w * whr[j].w;
        az += hv.x * whz[j].x + hv.y * whz[j].y + hv.z * whz[j].z + hv.w * whz[j].w;
        an += hv.x * whn[j].x + hv.y * whn[j].y + hv.z * whn[j].z + hv.w * whn[j].w;
      }
      ar += __shfl_xor(ar, 1); ar += __shfl_xor(ar, 2);
      az += __shfl_xor(az, 1); az += __shfl_xor(az, 2);
      an += __shfl_xor(an, 1); an += __shfl_xor(an, 2);
      if (q4 == 0) {
        float ghr = ar + sm.bhh[o4];
        float ghz = az + sm.bhh[NH + o4];
        float ghn = an + sm.bhh[2 * NH + o4];
        float r0 = sm.refin[0], r1 = sm.refin[1];
        float gir = r0 * sm.Gpre[o4] + r1 * sm.Gpre[384 + o4] + sm.Gpre[768 + o4];
        float giz = r0 * sm.Gpre[NH + o4] + r1 * sm.Gpre[384 + NH + o4] + sm.Gpre[768 + NH + o4];
        float gin = r0 * sm.Gpre[2 * NH + o4] + r1 * sm.Gpre[384 + 2 * NH + o4] + sm.Gpre[768 + 2 * NH + o4];
        // recurrent path keeps libm precision (h feeds back 63 steps)
        float r = 1.f / (1.f + expf(-(gir + ghr)));
        float z = 1.f / (1.f + expf(-(giz + ghz)));
        float n = tanhf(gin + r * ghn);
        float hold = sm.hbuf[cur][padh(o4)];
        sm.hbuf[cur ^ 1][padh(o4)] = (1.f - z) * n + z * hold;
      }
    }
    __syncthreads();
    // B: atth = h @ W_a[H:] (reg weights), quad-shfl
    {
      float acc = 0.f;
      const float* hp = sm.hbuf[cur ^ 1] + 36 * q4;
#pragma unroll
      for (int j = 0; j < 8; ++j) {
        float4 hv = *(const float4*)(hp + 4 * j);
        acc += hv.x * wa2r[4 * j] + hv.y * wa2r[4 * j + 1] +
               hv.z * wa2r[4 * j + 2] + hv.w * wa2r[4 * j + 3];
      }
      acc += __shfl_xor(acc, 1); acc += __shfl_xor(acc, 2);
      if (q4 == 0) sm.atth[padh(o4)] = acc;
    }
    __syncthreads();
    // C: attention tanh-dot, octet-shfl reduce -> red[s]
    {
      const float* pa = sm.preA + s8 * PITCH + 16 * q8;
      const float* ah = sm.atth + po8;
      const float* vv = sm.va + po8;
      float acc = 0.f;
#pragma unroll
      for (int u = 0; u < 4; ++u) {
        float4 a = *(const float4*)(pa + 4 * u);
        float4 hh = *(const float4*)(ah + 4 * u);
        float4 vw = *(const float4*)(vv + 4 * u);
        acc += ftanh(a.x + hh.x) * vw.x + ftanh(a.y + hh.y) * vw.y +
               ftanh(a.z + hh.z) * vw.z + ftanh(a.w + hh.w) * vw.w;
      }
      acc += __shfl_xor(acc, 1); acc += __shfl_xor(acc, 2); acc += __shfl_xor(acc, 4);
      if (q8 == 0) sm.red[s8] = acc;
    }
    __syncthreads();
    // softmax over s (wave 0)
    if (t < NS) {
      float e = sm.red[t];
      float m = e;
#pragma unroll
      for (int off = 32; off > 0; off >>= 1) m = fmaxf(m, __shfl_xor(m, off));
      float p = __expf(e - m);
      float ssum = p;
#pragma unroll
      for (int off = 32; off > 0; off >>= 1) ssum += __shfl_xor(ssum, off);
      sm.attn[t] = p / ssum;
    }
    __syncthreads();
    // D: ctx = attn @ IH (reg-cached IH), quad-shfl
    {
      float acc = 0.f;
      const float* ap = sm.attn + 16 * q4;
#pragma unroll
      for (int g = 0; g < 4; ++g) {
        float4 av = *(const float4*)(ap + 4 * g);
        acc += av.x * ihr[4 * g] + av.y * ihr[4 * g + 1] +
               av.z * ihr[4 * g + 2] + av.w * ihr[4 * g + 3];
      }
      acc += __shfl_xor(acc, 1); acc += __shfl_xor(acc, 2);
      if (q4 == 0) sm.ctx[o4] = acc;
    }
    __syncthreads();
    // E1: fc1 partials = ctx @ W1[:H] (streamed; L2-resident shared 131KB)
    {
      float4 acc = {0.f, 0.f, 0.f, 0.f};
      const float* w1p = W1 + (16 * qE1) * 256 + oE1;
#pragma unroll
      for (int k4 = 0; k4 < 4; ++k4) {
        float4 cv = *(const float4*)(sm.ctx + 16 * qE1 + 4 * k4);
        float cs[4] = {cv.x, cv.y, cv.z, cv.w};
#pragma unroll
        for (int u = 0; u < 4; ++u) {
          float4 w = *(const float4*)(w1p + (4 * k4 + u) * 256);
          acc.x += cs[u] * w.x; acc.y += cs[u] * w.y;
          acc.z += cs[u] * w.z; acc.w += cs[u] * w.w;
        }
      }
      *(float4*)(sm.red + qE1 * 256 + oE1) = acc;
    }
    __syncthreads();
    if (t < 256) {  // E1sum (+ zw1 + refh@W1ref via E1ref)
      float s = 0.f;
#pragma unroll
      for (int q = 0; q < 8; ++q) s += sm.red[q * 256 + t];
      float r0 = sm.refin[0], r1 = sm.refin[1];
      sm.fc1[t] = s + sm.zw1[t] + r0 * sm.E1ref[t] + r1 * sm.E1ref[256 + t] + sm.E1ref[512 + t];
    }
    __syncthreads();
    // E2: fco partials = fc1 @ W2 (streamed; L2-resident shared 131KB)
    {
      float4 acc = {0.f, 0.f, 0.f, 0.f};
      const float* w2p = W2 + (16 * qB) * NH + ob;
#pragma unroll
      for (int k4 = 0; k4 < 4; ++k4) {
        float4 fv = *(const float4*)(sm.fc1 + 16 * qB + 4 * k4);
        float fs[4] = {fv.x, fv.y, fv.z, fv.w};
#pragma unroll
        for (int u = 0; u < 4; ++u) {
          float4 w = *(const float4*)(w2p + (4 * k4 + u) * NH);
          acc.x += fs[u] * w.x; acc.y += fs[u] * w.y;
          acc.z += fs[u] * w.z; acc.w += fs[u] * w.w;
        }
      }
      *(float4*)(sm.red + qB * NH + ob) = acc;
    }
    __syncthreads();
    if (t < NH) {  // E2sum -> padded fco
      float s = 0.f;
#pragma unroll
      for (int q = 0; q < 16; ++q) s += sm.red[q * NH + t];
      sm.fcop[padh(t)] = s + sm.b2s[t];
    }
    __syncthreads();
    // F: ptrh = fco @ Wp[H:] (reg weights), quad-shfl
    {
      float acc = 0.f;
      const float* fp = sm.fcop + 36 * q4;
#pragma unroll
      for (int j = 0; j < 8; ++j) {
        float4 fv = *(const float4*)(fp + 4 * j);
        acc += fv.x * wpr[4 * j] + fv.y * wpr[4 * j + 1] +
               fv.z * wpr[4 * j + 2] + fv.w * wpr[4 * j + 3];
      }
      acc += __shfl_xor(acc, 1); acc += __shfl_xor(acc, 2);
      if (q4 == 0) sm.ptrh[padh(o4)] = acc;
    }
    __syncthreads();
    // G: pointer tanh-dot, octet-shfl reduce -> red[s]
    {
      const float* pp = sm.preP + s8 * PITCH + 16 * q8;
      const float* ph = sm.ptrh + po8;
      const float* vv = sm.vpv + po8;
      float acc = 0.f;
#pragma unroll
      for (int u = 0; u < 4; ++u) {
        float4 a = *(const float4*)(pp + 4 * u);
        float4 hh = *(const float4*)(ph + 4 * u);
        float4 vw = *(const float4*)(vv + 4 * u);
        acc += ftanh(a.x + hh.x) * vw.x + ftanh(a.y + hh.y) * vw.y +
               ftanh(a.z + hh.z) * vw.z + ftanh(a.w + hh.w) * vw.w;
      }
      acc += __shfl_xor(acc, 1); acc += __shfl_xor(acc, 2); acc += __shfl_xor(acc, 4);
      if (q8 == 0) sm.red[s8] = acc;
    }
    __syncthreads();
    // H: masked log-softmax, argmax (first-index tie), outputs, state update
    if (t < NS) {
      float lg = sm.red[t];
      float ml = (sm.maskv[t] > 0.5f) ? lg : -INFINITY;
      float m = ml;
      int mi = t;
#pragma unroll
      for (int off = 32; off > 0; off >>= 1) {
        float om = __shfl_xor(m, off);
        int oi = __shfl_xor(mi, off);
        if (om > m || (om == m && oi < mi)) { m = om; mi = oi; }
      }
      float p = __expf(ml - m);
      float ssum = p;
#pragma unroll
      for (int off = 32; off > 0; off >>= 1) ssum += __shfl_xor(ssum, off);
      int ptr = sm.sol[step];
      float pv = __shfl(ml, ptr);
      if (t == 0) {
        out[b * NS + step] = (float)mi;
        out[NB * NS + b * NSTEPS + (step - 1)] = pv - m - __logf(ssum);
        sm.maskv[ptr] = 0.0f;
        sm.refin[0] = sm.inst[2 * ptr];
        sm.refin[1] = sm.inst[2 * ptr + 1];
      }
    }
    cur ^= 1;
  }
}

extern "C" void kernel_launch(void* const* d_in, const int* in_sizes, int n_in,
                              void* d_out, int out_size, void* d_ws,
                              size_t ws_size, hipStream_t stream) {
  (void)in_sizes; (void)n_in; (void)out_size; (void)d_ws; (void)ws_size;
  const float* instance = (const float*)d_in[0];
  const int*   solution = (const int*)d_in[1];
  const float* Z        = (const float*)d_in[2];
  const float* IH       = (const float*)d_in[3];
  const float* last_hh  = (const float*)d_in[4];
  const float* W_emb    = (const float*)d_in[5];
  const float* b_emb    = (const float*)d_in[6];
  const float* W_ih     = (const float*)d_in[7];
  const float* W_hh     = (const float*)d_in[8];
  const float* b_ih     = (const float*)d_in[9];
  const float* b_hh     = (const float*)d_in[10];
  const float* W_a      = (const float*)d_in[11];
  const float* v_a      = (const float*)d_in[12];
  const float* W1       = (const float*)d_in[13];
  const float* b1       = (const float*)d_in[14];
  const float* W2       = (const float*)d_in[15];
  const float* b2       = (const float*)d_in[16];
  const float* Wp       = (const float*)d_in[17];
  const float* vp       = (const float*)d_in[18];
  float* out = (float*)d_out;

  const int shmem = (int)sizeof(SM);
  static_assert(sizeof(SM) <= 160 * 1024, "LDS overlay too big");
  hipFuncSetAttribute((const void*)decoder_kernel,
                      hipFuncAttributeMaxDynamicSharedMemorySize, shmem);
  decoder_kernel<<<NB, 512, shmem, stream>>>(
      instance, solution, Z, IH, last_hh, W_emb, b_emb, W_ih, W_hh, b_ih, b_hh,
      W_a, v_a, W1, b1, W2, b2, Wp, vp, out);
}